// Round 7
// baseline (219.863 us; speedup 1.0000x reference)
//
#include <hip/hip_runtime.h>

// Problem constants (fixed by the reference module)
#define K_   64
#define C_   64
#define W_   128
#define P_   4
#define B_   16
#define W2_  136                 // W + 2*PAD
#define OUTSP 18496              // W2*W2 elements per (k,c) plane
#define CWW  1048576             // C*W*W — cube stride per face (k index)

// Quads (4-float units). Units = 256 quads (64 lanes x 4 sub-quads).
// Interior: 16,777,216 quads = 65,536 units
// TB halo : 1,114,112 quads (= 4352 units exactly; 1114112 % 256 == 0)
// LR halo : 1,048,576 quads (= 4096 units)          -> 8448 halo units
// Unit map U -> (g=U/9, r=U%9): r<8 -> interior unit g*8+r (guard <65536),
// r==8 -> halo unit g. 8:1 interleave keeps gathers flowing alongside streams.
#define NQ_TB  1114112
#define NU_INT 65536
#define NU_HALO 8448
#define N_UNITS (NU_HALO * 9)     // 76,032
#define N_WID   (N_UNITS * 64)    // 4,866,048 thread-iterations

typedef int   int4n   __attribute__((ext_vector_type(4)));
typedef float float4n __attribute__((ext_vector_type(4)));

__global__ void fused_pad_kernel(const float* __restrict__ cube,
                                 const int* __restrict__ to_process,
                                 const int* __restrict__ px_tb,
                                 const int* __restrict__ px_lr,
                                 const int* __restrict__ fi_tb,
                                 const int* __restrict__ fi_lr,
                                 float* __restrict__ out) {
    __shared__ int inv[6 * B_];   // global face id -> cube row, -1 absent
    __shared__ int tp[K_];
    const int tid = threadIdx.x;
    if (tid < 6 * B_) inv[tid] = -1;
    if (tid < K_)     tp[tid]  = to_process[tid];
    __syncthreads();
    if (tid < K_)     inv[tp[tid]] = tid;
    __syncthreads();

    const int stride = gridDim.x * blockDim.x;
    for (int t = blockIdx.x * blockDim.x + tid; t < N_WID; t += stride) {
        int U = t >> 6;            // unit index (wave-uniform)
        int l = t & 63;            // lane
        int g = U / 9;
        int r = U - 9 * g;

        if (r < 8) {
            // ---- interior unit: 4 coalesced sub-loads in flight ----
            int iu = (g << 3) + r;
            if (iu < NU_INT) {
                int id0 = (iu << 8) + l;
                const float4n* c4 = reinterpret_cast<const float4n*>(cube);
                float4n v0 = c4[id0];
                float4n v1 = c4[id0 +  64];
                float4n v2 = c4[id0 + 128];
                float4n v3 = c4[id0 + 192];
#define STORE_INT(vv, idd) {                                                  \
            int q  = (idd) & 31;                                              \
            int R  = (idd) >> 5;                                              \
            int rr = R & (W_ - 1);                                            \
            int kc = R >> 7;                                                  \
            __builtin_nontemporal_store(vv, reinterpret_cast<float4n*>(       \
                out + (size_t)kc * OUTSP + (size_t)(rr + P_) * W2_ + P_) + q); }
                STORE_INT(v0, id0)
                STORE_INT(v1, id0 + 64)
                STORE_INT(v2, id0 + 128)
                STORE_INT(v3, id0 + 192)
#undef STORE_INT
            }
        } else {
            int id0 = (g << 8) + l;   // first sub-quad id (units never straddle TB/LR)
            if (id0 < NQ_TB) {
                // ---- TB halo unit: 8 idx loads -> 16 gathers -> 4 stores ----
                int4n fiv[4], pxv[4];
                int kkA[4], ccA[4], rrA[4], c4A[4], b6A[4];
#pragma unroll
                for (int j = 0; j < 4; ++j) {
                    int id   = id0 + j * 64;
                    int col4 = id % 34;
                    int rest = id / 34;
                    int rr   = rest & 7;  rest >>= 3;
                    int cc   = rest & 63;
                    int kk   = rest >> 6;
                    int gf = tp[kk];
                    int b  = gf / 6;
                    int fb = gf - 6 * b;
                    kkA[j] = kk; ccA[j] = cc; rrA[j] = rr; c4A[j] = col4;
                    b6A[j] = 6 * b;
                    fiv[j] = *reinterpret_cast<const int4n*>(
                        fi_tb + (fb * 2 * P_ + rr) * W2_ + col4 * 4);
                    pxv[j] = *reinterpret_cast<const int4n*>(
                        px_tb + ((fb * C_ + cc) * 2 * P_ + rr) * W2_ + col4 * 4);
                }
                float4n v[4];
#pragma unroll
                for (int j = 0; j < 4; ++j) {
                    int f0 = inv[fiv[j].x + b6A[j]];
                    int f1 = inv[fiv[j].y + b6A[j]];
                    int f2 = inv[fiv[j].z + b6A[j]];
                    int f3 = inv[fiv[j].w + b6A[j]];
                    v[j].x = (f0 >= 0) ? cube[(size_t)f0 * CWW + pxv[j].x] : 0.0f;
                    v[j].y = (f1 >= 0) ? cube[(size_t)f1 * CWW + pxv[j].y] : 0.0f;
                    v[j].z = (f2 >= 0) ? cube[(size_t)f2 * CWW + pxv[j].z] : 0.0f;
                    v[j].w = (f3 >= 0) ? cube[(size_t)f3 * CWW + pxv[j].w] : 0.0f;
                }
#pragma unroll
                for (int j = 0; j < 4; ++j) {
                    int outr = (rrA[j] < P_) ? rrA[j] : (W_ + rrA[j]);
                    __builtin_nontemporal_store(v[j], reinterpret_cast<float4n*>(
                        out + (size_t)(kkA[j] * C_ + ccA[j]) * OUTSP
                            + (size_t)outr * W2_ + c4A[j] * 4));
                }
            } else {
                // ---- LR halo unit ----
                int4n fiv[4], pxv[4];
                int kkA[4], ccA[4], rrA[4], qA[4], b6A[4];
#pragma unroll
                for (int j = 0; j < 4; ++j) {
                    int u  = (id0 + j * 64) - NQ_TB;
                    int q  = u & 1;
                    int rr = (u >> 1) & (W_ - 1);
                    int cc = (u >> 8) & 63;
                    int kk = u >> 14;
                    int gf = tp[kk];
                    int b  = gf / 6;
                    int fb = gf - 6 * b;
                    kkA[j] = kk; ccA[j] = cc; rrA[j] = rr; qA[j] = q;
                    b6A[j] = 6 * b;
                    fiv[j] = *reinterpret_cast<const int4n*>(
                        fi_lr + (fb * W_ + rr) * 2 * P_ + q * 4);
                    pxv[j] = *reinterpret_cast<const int4n*>(
                        px_lr + ((fb * C_ + cc) * W_ + rr) * 2 * P_ + q * 4);
                }
                float4n v[4];
#pragma unroll
                for (int j = 0; j < 4; ++j) {
                    int f0 = inv[fiv[j].x + b6A[j]];
                    int f1 = inv[fiv[j].y + b6A[j]];
                    int f2 = inv[fiv[j].z + b6A[j]];
                    int f3 = inv[fiv[j].w + b6A[j]];
                    v[j].x = (f0 >= 0) ? cube[(size_t)f0 * CWW + pxv[j].x] : 0.0f;
                    v[j].y = (f1 >= 0) ? cube[(size_t)f1 * CWW + pxv[j].y] : 0.0f;
                    v[j].z = (f2 >= 0) ? cube[(size_t)f2 * CWW + pxv[j].z] : 0.0f;
                    v[j].w = (f3 >= 0) ? cube[(size_t)f3 * CWW + pxv[j].w] : 0.0f;
                }
#pragma unroll
                for (int j = 0; j < 4; ++j) {
                    int outc = qA[j] ? (W_ + P_) : 0;
                    __builtin_nontemporal_store(v[j], reinterpret_cast<float4n*>(
                        out + (size_t)(kkA[j] * C_ + ccA[j]) * OUTSP
                            + (size_t)(rrA[j] + P_) * W2_ + outc));
                }
            }
        }
    }
}

extern "C" void kernel_launch(void* const* d_in, const int* in_sizes, int n_in,
                              void* d_out, int out_size, void* d_ws, size_t ws_size,
                              hipStream_t stream) {
    const float* cube         = (const float*)d_in[0];
    const int*   to_process   = (const int*)d_in[1];
    // d_in[2] = batch_size (scalar, fixed = 16)
    const int*   pixel_idx_tb = (const int*)d_in[3];
    const int*   pixel_idx_lr = (const int*)d_in[4];
    const int*   face_idx_tb  = (const int*)d_in[5];
    const int*   face_idx_lr  = (const int*)d_in[6];
    float*       out          = (float*)d_out;

    // 2048 blocks x 256 threads; ~9.3 units/thread, 4x MLP within each unit.
    fused_pad_kernel<<<2048, 256, 0, stream>>>(
        cube, to_process, pixel_idx_tb, pixel_idx_lr,
        face_idx_tb, face_idx_lr, out);
}